// Round 2
// baseline (4461.828 us; speedup 1.0000x reference)
//
#include <hip/hip_runtime.h>
#include <hip/hip_bf16.h>

typedef unsigned int u32;
typedef unsigned short u16;

__device__ __forceinline__ float u16tof(u16 u){ return __uint_as_float(((u32)u) << 16); }
__device__ __forceinline__ u16 ftobf(float f){
  u32 b = __float_as_uint(f);
  return (u16)((b + 0x7FFFu + ((b >> 16) & 1u)) >> 16);
}
__device__ __forceinline__ float ldf(const void* p, int i, int isbf){
  return isbf ? u16tof(((const u16*)p)[i]) : ((const float*)p)[i];
}
__device__ __forceinline__ u32 flipf(float x){
  u32 b = __float_as_uint(x);
  return (b & 0x80000000u) ? ~b : (b | 0x80000000u);
}
__device__ __forceinline__ float unflipf(u32 u){
  return (u & 0x80000000u) ? __uint_as_float(u & 0x7fffffffu) : __uint_as_float(~u);
}

// ---- dtype detect: bits[7:14] of each word are an exponent field iff bf16-packed ----
__global__ __launch_bounds__(256) void k_detect(const u32* __restrict__ w, int nwords, int* __restrict__ flag){
  __shared__ int cnt;
  if (threadIdx.x == 0) cnt = 0;
  __syncthreads();
  int local = 0;
  for (int i = threadIdx.x; i < nwords; i += 256){
    u32 e = (w[i] >> 7) & 0xFFu;
    if (e >= 100u && e < 127u) local++;
  }
  atomicAdd(&cnt, local);
  __syncthreads();
  if (threadIdx.x == 0) *flag = (cnt > nwords / 2) ? 1 : 0;
}

// ---- x -> fp32 H (convert or copy) ----
__global__ __launch_bounds__(256) void k_cvt(const void* __restrict__ in, float4* __restrict__ out, int n4,
                                             const int* __restrict__ fl){
  const int isbf = *fl;
  int i = blockIdx.x * 256 + threadIdx.x;
  if (i >= n4) return;
  if (isbf){
    ushort4 u = ((const ushort4*)in)[i];
    out[i] = make_float4(u16tof(u.x), u16tof(u.y), u16tof(u.z), u16tof(u.w));
  } else {
    out[i] = ((const float4*)in)[i];
  }
}

// ---- degree count over dst ----
__global__ __launch_bounds__(256) void k_count(const int* __restrict__ dst, int* __restrict__ cnt, int nE){
  int i = blockIdx.x * 256 + threadIdx.x;
  if (i < nE) atomicAdd(&cnt[dst[i]], 1);
}

__global__ __launch_bounds__(256) void k_dinv(const int* __restrict__ cnt, float* __restrict__ dinv, int n){
  int i = blockIdx.x * 256 + threadIdx.x;
  if (i < n) dinv[i] = rsqrtf((float)cnt[i] + 1.0f);
}

// ---- exclusive scan of cnt -> boff ----
__global__ __launch_bounds__(256) void k_scan1(const int* __restrict__ cnt, int* __restrict__ boff,
                                               int* __restrict__ bsum, int n){
  __shared__ int sm[256];
  int t = threadIdx.x;
  int i = blockIdx.x * 256 + t;
  int v = (i < n) ? cnt[i] : 0;
  sm[t] = v; __syncthreads();
  for (int off = 1; off < 256; off <<= 1){
    int add = (t >= off) ? sm[t - off] : 0;
    __syncthreads();
    sm[t] += add;
    __syncthreads();
  }
  if (i < n) boff[i] = sm[t] - v;
  if (t == 255) bsum[blockIdx.x] = sm[255];
}

__global__ __launch_bounds__(512) void k_scan2(int* __restrict__ bsum, int nb){
  __shared__ int sm[512];
  int t = threadIdx.x;
  int v = (t < nb) ? bsum[t] : 0;
  sm[t] = v; __syncthreads();
  for (int off = 1; off < 512; off <<= 1){
    int add = (t >= off) ? sm[t - off] : 0;
    __syncthreads();
    sm[t] += add;
    __syncthreads();
  }
  if (t < nb) bsum[t] = sm[t] - v;
}

__global__ __launch_bounds__(256) void k_scan3(int* __restrict__ boff, const int* __restrict__ bsum, int n, int nE){
  int i = blockIdx.x * 256 + threadIdx.x;
  if (i < n) boff[i] += bsum[blockIdx.x];
  if (i == 0) boff[n] = nE;
}

// ---- counting-sort edges by dst: eid[slot] = src ----
__global__ __launch_bounds__(256) void k_fill(const int* __restrict__ src, const int* __restrict__ dst,
                                              int* __restrict__ cnt, const int* __restrict__ boff,
                                              int* __restrict__ eid, int nE){
  int e = blockIdx.x * 256 + threadIdx.x;
  if (e >= nE) return;
  int d = dst[e];
  int old = atomicSub(&cnt[d], 1);
  eid[boff[d] + old - 1] = src[e];
}

// ---- C[n,128] = A[n,128] @ W[layer][128,128] (+bias). W staged fp32 in LDS. ----
__global__ __launch_bounds__(256) void k_matmul(const float* __restrict__ A, const void* __restrict__ W,
                                                int layer, const void* __restrict__ bias,
                                                float* __restrict__ C, int n, const int* __restrict__ fl){
  const int isbf = *fl;
  const int wbase = layer * 128 * 128;   // element offset, dtype-agnostic
  __shared__ float wl[128 * 128];
  if (isbf){
    const ushort4* W4 = (const ushort4*)((const u16*)W + wbase);
    for (int t = threadIdx.x; t < 128 * 128 / 4; t += 256){
      ushort4 u = W4[t];
      *(float4*)&wl[t * 4] = make_float4(u16tof(u.x), u16tof(u.y), u16tof(u.z), u16tof(u.w));
    }
  } else {
    const float4* W4 = (const float4*)((const float*)W + wbase);
    for (int t = threadIdx.x; t < 128 * 128 / 4; t += 256){
      *(float4*)&wl[t * 4] = W4[t];
    }
  }
  __syncthreads();
  const int wave = threadIdx.x >> 6, lane = threadIdx.x & 63;
  const int base = blockIdx.x * 64 + wave * 16;
  for (int rr = 0; rr < 16; rr += 4){
    const int r0 = base + rr;
    if (r0 >= n) return;
    const float4* Ar[4];
    #pragma unroll
    for (int j = 0; j < 4; ++j){
      int r = r0 + j; if (r > n - 1) r = n - 1;
      Ar[j] = (const float4*)(A + (size_t)r * 128);
    }
    float acc[4][2] = {{0.f,0.f},{0.f,0.f},{0.f,0.f},{0.f,0.f}};
    float4 a[4], an[4];
    #pragma unroll
    for (int j = 0; j < 4; ++j) a[j] = Ar[j][0];
    for (int k4 = 0; k4 < 32; ++k4){
      if (k4 < 31){
        #pragma unroll
        for (int j = 0; j < 4; ++j) an[j] = Ar[j][k4 + 1];
      }
      #pragma unroll
      for (int kk = 0; kk < 4; ++kk){
        const float2 w = *(const float2*)&wl[((k4 << 2) + kk) * 128 + (lane << 1)];
        #pragma unroll
        for (int j = 0; j < 4; ++j){
          const float av = (kk == 0) ? a[j].x : (kk == 1) ? a[j].y : (kk == 2) ? a[j].z : a[j].w;
          acc[j][0] = fmaf(av, w.x, acc[j][0]);
          acc[j][1] = fmaf(av, w.y, acc[j][1]);
        }
      }
      #pragma unroll
      for (int j = 0; j < 4; ++j) a[j] = an[j];
    }
    float b0 = 0.f, b1 = 0.f;
    if (bias){ b0 = ldf(bias, lane << 1, isbf); b1 = ldf(bias, (lane << 1) + 1, isbf); }
    #pragma unroll
    for (int j = 0; j < 4; ++j){
      if (r0 + j < n){
        *(float2*)&C[(size_t)(r0 + j) * 128 + (lane << 1)] = make_float2(acc[j][0] + b0, acc[j][1] + b1);
      }
    }
  }
}

// ---- H[i] = sum_{e->i} T[src]*dinv[src]*dinv[i] + T[i]*dinv[i]^2 + b[layer]; opt relu ----
__global__ __launch_bounds__(256) void k_gather(const float* __restrict__ T, const int* __restrict__ boff,
                                                const int* __restrict__ eid, const float* __restrict__ dinv,
                                                const void* __restrict__ bias, int layer,
                                                float* __restrict__ H, int n, int relu,
                                                const int* __restrict__ fl){
  const int node = blockIdx.x * 4 + (threadIdx.x >> 6);
  if (node >= n) return;
  const int isbf = *fl;
  const int bbase = layer * 128;
  const int lane = threadIdx.x & 63;
  const float di = dinv[node];
  const float2 sv = ((const float2*)(T + (size_t)node * 128))[lane];
  float acc0 = sv.x * di * di, acc1 = sv.y * di * di;
  const int b0 = boff[node], b1 = boff[node + 1];
  for (int j = b0; j < b1; ++j){
    const int s = eid[j];
    const float en = dinv[s] * di;
    const float2 v = ((const float2*)(T + (size_t)s * 128))[lane];
    acc0 = fmaf(v.x, en, acc0);
    acc1 = fmaf(v.y, en, acc1);
  }
  acc0 += ldf(bias, bbase + (lane << 1), isbf);
  acc1 += ldf(bias, bbase + (lane << 1) + 1, isbf);
  if (relu){ acc0 = fmaxf(acc0, 0.f); acc1 = fmaxf(acc1, 0.f); }
  *(float2*)&H[(size_t)node * 128 + (lane << 1)] = make_float2(acc0, acc1);
}

// ---- s[i] = relu(T[i]) . w2 + b2, masked ----
__global__ __launch_bounds__(256) void k_score(const float* __restrict__ T, const void* __restrict__ w2,
                                               const void* __restrict__ b2, const int* __restrict__ mask,
                                               float* __restrict__ s, int n, const int* __restrict__ fl){
  const int node = blockIdx.x * 4 + (threadIdx.x >> 6);
  if (node >= n) return;
  const int isbf = *fl;
  const int lane = threadIdx.x & 63;
  const float* row = T + (size_t)node * 128;
  float sum = fmaxf(row[lane], 0.f) * ldf(w2, lane, isbf)
            + fmaxf(row[lane + 64], 0.f) * ldf(w2, lane + 64, isbf);
  #pragma unroll
  for (int off = 32; off > 0; off >>= 1) sum += __shfl_down(sum, off);
  if (lane == 0){
    float sc = sum + ldf(b2, 0, isbf);
    if (mask[node] == 0) sc = -1e9f;
    s[node] = sc;
  }
}

// ---- segment softmax ----
__global__ __launch_bounds__(256) void k_smax(const float* __restrict__ s, const int* __restrict__ batch,
                                              u32* __restrict__ mu, int n){
  int i = blockIdx.x * 256 + threadIdx.x;
  if (i < n) atomicMax(&mu[batch[i]], flipf(s[i]));
}

__global__ __launch_bounds__(256) void k_sexp(float* __restrict__ s, const int* __restrict__ batch,
                                              const u32* __restrict__ mu, float* __restrict__ z, int n){
  int i = blockIdx.x * 256 + threadIdx.x;
  if (i >= n) return;
  int b = batch[i];
  float e = expf(s[i] - unflipf(mu[b]));
  s[i] = e;
  atomicAdd(&z[b], e);
}

__global__ __launch_bounds__(256) void k_sout(const float* __restrict__ s, const int* __restrict__ batch,
                                              const float* __restrict__ z, void* __restrict__ out, int n,
                                              const int* __restrict__ fl){
  int i = blockIdx.x * 256 + threadIdx.x;
  if (i >= n) return;
  const int isbf = *fl;
  float v = s[i] / z[batch[i]];
  if (isbf) ((u16*)out)[i] = ftobf(v);
  else      ((float*)out)[i] = v;
}

extern "C" void kernel_launch(void* const* d_in, const int* in_sizes, int n_in,
                              void* d_out, int out_size, void* d_ws, size_t ws_size,
                              hipStream_t stream){
  const void* x    = d_in[0];
  const int* ei    = (const int*)d_in[1];
  const int* batch = (const int*)d_in[2];
  const int* mask  = (const int*)d_in[3];
  const void* gw   = d_in[4];
  const void* gb   = d_in[5];
  const void* l1w  = d_in[6];
  const void* l1b  = d_in[7];
  const void* l2w  = d_in[8];
  const void* l2b  = d_in[9];

  const int N = in_sizes[2];
  const int E = in_sizes[1] / 2;
  const int D = 128;
  const int L = in_sizes[4] / (D * D);
  const int G = 1000;   // from reference; not derivable from sizes

  char* p = (char*)d_ws;
  float* H    = (float*)p; p += (size_t)N * D * sizeof(float);
  float* T    = (float*)p; p += (size_t)N * D * sizeof(float);
  float* dinv = (float*)p; p += (size_t)N * sizeof(float);
  float* sbuf = (float*)p; p += (size_t)N * sizeof(float);
  int*  cnt   = (int*)p;   p += (size_t)N * sizeof(int);
  int*  boff  = (int*)p;   p += (size_t)(N + 1) * sizeof(int);
  int*  bsum  = (int*)p;   p += 1024 * sizeof(int);
  int*  eid   = (int*)p;   p += (size_t)E * sizeof(int);
  u32*  mu    = (u32*)p;   p += (size_t)G * sizeof(u32);
  float* z    = (float*)p; p += (size_t)G * sizeof(float);
  int*  flag  = (int*)p;   p += 256;

  const int* src  = ei;
  const int* dstp = ei + E;

  hipMemsetAsync(cnt, 0, (size_t)N * sizeof(int), stream);
  hipMemsetAsync(mu, 0, (size_t)G * sizeof(u32), stream);
  hipMemsetAsync(z, 0, (size_t)G * sizeof(float), stream);

  const int n4  = N * D / 4;
  const int nb1 = (N + 255) / 256;
  const int mmg = (N + 63) / 64;
  const int ndg = (N + 3) / 4;

  // dtype detect on gcn_w (first 4096 words are in-bounds under either dtype)
  k_detect<<<1, 256, 0, stream>>>((const u32*)gw, 4096, flag);

  k_cvt<<<(n4 + 255) / 256, 256, 0, stream>>>(x, (float4*)H, n4, flag);
  k_count<<<(E + 255) / 256, 256, 0, stream>>>(dstp, cnt, E);
  k_scan1<<<nb1, 256, 0, stream>>>(cnt, boff, bsum, N);
  k_scan2<<<1, 512, 0, stream>>>(bsum, nb1);
  k_scan3<<<nb1, 256, 0, stream>>>(boff, bsum, N, E);
  k_dinv<<<nb1, 256, 0, stream>>>(cnt, dinv, N);     // before k_fill destroys cnt
  k_fill<<<(E + 255) / 256, 256, 0, stream>>>(src, dstp, cnt, boff, eid, E);

  for (int l = 0; l < L; ++l){
    k_matmul<<<mmg, 256, 0, stream>>>(H, gw, l, nullptr, T, N, flag);
    k_gather<<<ndg, 256, 0, stream>>>(T, boff, eid, dinv, gb, l, H, N, (l < L - 1) ? 1 : 0, flag);
  }
  k_matmul<<<mmg, 256, 0, stream>>>(H, l1w, 0, l1b, T, N, flag);
  k_score<<<ndg, 256, 0, stream>>>(T, l2w, l2b, mask, sbuf, N, flag);
  k_smax<<<nb1, 256, 0, stream>>>(sbuf, batch, mu, N);
  k_sexp<<<nb1, 256, 0, stream>>>(sbuf, batch, mu, z, N);
  k_sout<<<nb1, 256, 0, stream>>>(sbuf, batch, z, d_out, N, flag);
}

// Round 3
// 628.717 us; speedup vs baseline: 7.0967x; 7.0967x over previous
//
#include <hip/hip_runtime.h>
#include <hip/hip_bf16.h>

typedef unsigned int u32;
typedef unsigned short u16;
typedef __attribute__((ext_vector_type(8))) short bf16x8;
typedef __attribute__((ext_vector_type(4))) float f32x4;

__device__ __forceinline__ float u16tof(u16 u){ return __uint_as_float(((u32)u) << 16); }
__device__ __forceinline__ u16 ftobf(float f){
  u32 b = __float_as_uint(f);
  return (u16)((b + 0x7FFFu + ((b >> 16) & 1u)) >> 16);
}
__device__ __forceinline__ float ldf(const void* p, int i, int isbf){
  return isbf ? u16tof(((const u16*)p)[i]) : ((const float*)p)[i];
}
__device__ __forceinline__ u32 flipf(float x){
  u32 b = __float_as_uint(x);
  return (b & 0x80000000u) ? ~b : (b | 0x80000000u);
}
__device__ __forceinline__ float unflipf(u32 u){
  return (u & 0x80000000u) ? __uint_as_float(u & 0x7fffffffu) : __uint_as_float(~u);
}

// ---- dtype detect: bits[7:14] of each word are an exponent field iff bf16-packed ----
__global__ __launch_bounds__(256) void k_detect(const u32* __restrict__ w, int nwords, int* __restrict__ flag){
  __shared__ int cnt;
  if (threadIdx.x == 0) cnt = 0;
  __syncthreads();
  int local = 0;
  for (int i = threadIdx.x; i < nwords; i += 256){
    u32 e = (w[i] >> 7) & 0xFFu;
    if (e >= 100u && e < 127u) local++;
  }
  atomicAdd(&cnt, local);
  __syncthreads();
  if (threadIdx.x == 0) *flag = (cnt > nwords / 2) ? 1 : 0;
}

// ---- weight prep: fragment-ordered bf16 Wf for matrices gw[0..L-1] and l1w ----
// Wf[b][((t*4+ks)*64+lane)*8 + j] = W_b[k][n],  k=ks*32+(lane>>4)*8+j, n=t*16+(lane&15)
__global__ __launch_bounds__(256) void k_wprep(const void* __restrict__ gw, const void* __restrict__ l1w,
                                               u16* __restrict__ Wf, int L, const int* __restrict__ fl){
  const int isbf = *fl;
  const int b = blockIdx.x;
  const void* src = (b < L) ? gw : l1w;
  const int sbase = (b < L) ? b * 16384 : 0;
  u16* dst = Wf + (size_t)b * 16384;
  for (int g = threadIdx.x; g < 2048; g += 256){
    const int t = g >> 8, ks = (g >> 6) & 3, lane = g & 63;
    const int n = t * 16 + (lane & 15);
    const int k0 = ks * 32 + ((lane >> 4) << 3);
    u16* d = dst + (size_t)g * 8;
    #pragma unroll
    for (int j = 0; j < 8; ++j){
      float v = ldf(src, sbase + (k0 + j) * 128 + n, isbf);
      d[j] = ftobf(v);
    }
  }
}

// ---- x -> bf16 Hb (copy or convert), 8 elems/thread ----
__global__ __launch_bounds__(256) void k_cvt(const void* __restrict__ in, u16* __restrict__ out, int n8,
                                             const int* __restrict__ fl){
  const int isbf = *fl;
  int i = blockIdx.x * 256 + threadIdx.x;
  if (i >= n8) return;
  if (isbf){
    ((uint4*)out)[i] = ((const uint4*)in)[i];
  } else {
    const float4 a = ((const float4*)in)[i * 2];
    const float4 b = ((const float4*)in)[i * 2 + 1];
    u16* o = out + (size_t)i * 8;
    o[0] = ftobf(a.x); o[1] = ftobf(a.y); o[2] = ftobf(a.z); o[3] = ftobf(a.w);
    o[4] = ftobf(b.x); o[5] = ftobf(b.y); o[6] = ftobf(b.z); o[7] = ftobf(b.w);
  }
}

// ---- degree count over dst ----
__global__ __launch_bounds__(256) void k_count(const int* __restrict__ dst, int* __restrict__ cnt, int nE){
  int i = blockIdx.x * 256 + threadIdx.x;
  if (i < nE) atomicAdd(&cnt[dst[i]], 1);
}

__global__ __launch_bounds__(256) void k_dinv(const int* __restrict__ cnt, float* __restrict__ dinv, int n){
  int i = blockIdx.x * 256 + threadIdx.x;
  if (i < n) dinv[i] = rsqrtf((float)cnt[i] + 1.0f);
}

// ---- exclusive scan of cnt -> boff ----
__global__ __launch_bounds__(256) void k_scan1(const int* __restrict__ cnt, int* __restrict__ boff,
                                               int* __restrict__ bsum, int n){
  __shared__ int sm[256];
  int t = threadIdx.x;
  int i = blockIdx.x * 256 + t;
  int v = (i < n) ? cnt[i] : 0;
  sm[t] = v; __syncthreads();
  for (int off = 1; off < 256; off <<= 1){
    int add = (t >= off) ? sm[t - off] : 0;
    __syncthreads();
    sm[t] += add;
    __syncthreads();
  }
  if (i < n) boff[i] = sm[t] - v;
  if (t == 255) bsum[blockIdx.x] = sm[255];
}

__global__ __launch_bounds__(512) void k_scan2(int* __restrict__ bsum, int nb){
  __shared__ int sm[512];
  int t = threadIdx.x;
  int v = (t < nb) ? bsum[t] : 0;
  sm[t] = v; __syncthreads();
  for (int off = 1; off < 512; off <<= 1){
    int add = (t >= off) ? sm[t - off] : 0;
    __syncthreads();
    sm[t] += add;
    __syncthreads();
  }
  if (t < nb) bsum[t] = sm[t] - v;
}

__global__ __launch_bounds__(256) void k_scan3(int* __restrict__ boff, const int* __restrict__ bsum, int n, int nE){
  int i = blockIdx.x * 256 + threadIdx.x;
  if (i < n) boff[i] += bsum[blockIdx.x];
  if (i == 0) boff[n] = nE;
}

// ---- counting-sort edges by dst: eid[slot] = src ----
__global__ __launch_bounds__(256) void k_fill(const int* __restrict__ src, const int* __restrict__ dst,
                                              int* __restrict__ cnt, const int* __restrict__ boff,
                                              int* __restrict__ eid, int nE){
  int e = blockIdx.x * 256 + threadIdx.x;
  if (e >= nE) return;
  int d = dst[e];
  int old = atomicSub(&cnt[d], 1);
  eid[boff[d] + old - 1] = src[e];
}

// ---- MFMA matmul: T[n,128] = A[n,128](bf16) @ W (fragment-ordered bf16) (+bias) ----
// wave -> 16 rows x 128 cols: 8 col-tiles x 4 K-steps of mfma_f32_16x16x32_bf16
__global__ __launch_bounds__(256) void k_mm(const u16* __restrict__ A, const u16* __restrict__ Wf,
                                            const void* __restrict__ bias, u16* __restrict__ T,
                                            int n, const int* __restrict__ fl){
  const int isbf = *fl;
  const int wave = threadIdx.x >> 6, lane = threadIdx.x & 63;
  const int m0 = blockIdx.x * 64 + wave * 16;
  int arow = m0 + (lane & 15); if (arow > n - 1) arow = n - 1;
  const u16* aptr = A + (size_t)arow * 128 + ((lane >> 4) << 3);

  f32x4 acc[8];
  #pragma unroll
  for (int t = 0; t < 8; ++t) acc[t] = (f32x4){0.f, 0.f, 0.f, 0.f};

  #pragma unroll
  for (int ks = 0; ks < 4; ++ks){
    const bf16x8 a = *(const bf16x8*)(aptr + ks * 32);
    #pragma unroll
    for (int t = 0; t < 8; ++t){
      const bf16x8 b = *(const bf16x8*)(Wf + (size_t)(((t * 4 + ks) * 64 + lane) * 8));
      acc[t] = __builtin_amdgcn_mfma_f32_16x16x32_bf16(a, b, acc[t], 0, 0, 0);
    }
  }

  const int quad = lane >> 4, col0 = lane & 15;
  #pragma unroll
  for (int t = 0; t < 8; ++t){
    const int col = t * 16 + col0;
    const float bv = bias ? ldf(bias, col, isbf) : 0.f;
    #pragma unroll
    for (int r = 0; r < 4; ++r){
      const int row = m0 + quad * 4 + r;
      if (row < n) T[(size_t)row * 128 + col] = ftobf(acc[t][r] + bv);
    }
  }
}

// ---- H[i] = sum_{e->i} T[src]*dinv[src]*dinv[i] + T[i]*dinv[i]^2 + b[layer]; opt relu (bf16 rows) ----
__global__ __launch_bounds__(256) void k_gather(const u16* __restrict__ T, const int* __restrict__ boff,
                                                const int* __restrict__ eid, const float* __restrict__ dinv,
                                                const void* __restrict__ bias, int layer,
                                                u16* __restrict__ H, int n, int relu,
                                                const int* __restrict__ fl){
  const int node = blockIdx.x * 4 + (threadIdx.x >> 6);
  if (node >= n) return;
  const int isbf = *fl;
  const int lane = threadIdx.x & 63;
  const float di = dinv[node];
  const u32 sv = ((const u32*)(T + (size_t)node * 128))[lane];
  float acc0 = u16tof((u16)(sv & 0xffff)) * di * di;
  float acc1 = u16tof((u16)(sv >> 16)) * di * di;
  const int b0 = boff[node], b1 = boff[node + 1];
  for (int j = b0; j < b1; ++j){
    const int s = eid[j];
    const float en = dinv[s] * di;
    const u32 v = ((const u32*)(T + (size_t)s * 128))[lane];
    acc0 = fmaf(u16tof((u16)(v & 0xffff)), en, acc0);
    acc1 = fmaf(u16tof((u16)(v >> 16)), en, acc1);
  }
  const int bb = layer * 128 + (lane << 1);
  acc0 += ldf(bias, bb, isbf);
  acc1 += ldf(bias, bb + 1, isbf);
  if (relu){ acc0 = fmaxf(acc0, 0.f); acc1 = fmaxf(acc1, 0.f); }
  const u32 o = (u32)ftobf(acc0) | ((u32)ftobf(acc1) << 16);
  ((u32*)(H + (size_t)node * 128))[lane] = o;
}

// ---- s[i] = relu(T[i]) . w2 + b2, masked ----
__global__ __launch_bounds__(256) void k_score(const u16* __restrict__ T, const void* __restrict__ w2,
                                               const void* __restrict__ b2, const int* __restrict__ mask,
                                               float* __restrict__ s, int n, const int* __restrict__ fl){
  const int node = blockIdx.x * 4 + (threadIdx.x >> 6);
  if (node >= n) return;
  const int isbf = *fl;
  const int lane = threadIdx.x & 63;
  const u32 v = ((const u32*)(T + (size_t)node * 128))[lane];
  const int c = lane << 1;
  float sum = fmaxf(u16tof((u16)(v & 0xffff)), 0.f) * ldf(w2, c, isbf)
            + fmaxf(u16tof((u16)(v >> 16)), 0.f) * ldf(w2, c + 1, isbf);
  #pragma unroll
  for (int off = 32; off > 0; off >>= 1) sum += __shfl_down(sum, off);
  if (lane == 0){
    float sc = sum + ldf(b2, 0, isbf);
    if (mask[node] == 0) sc = -1e9f;
    s[node] = sc;
  }
}

// ---- segment softmax ----
__global__ __launch_bounds__(256) void k_smax(const float* __restrict__ s, const int* __restrict__ batch,
                                              u32* __restrict__ mu, int n){
  int i = blockIdx.x * 256 + threadIdx.x;
  if (i < n) atomicMax(&mu[batch[i]], flipf(s[i]));
}

__global__ __launch_bounds__(256) void k_sexp(float* __restrict__ s, const int* __restrict__ batch,
                                              const u32* __restrict__ mu, float* __restrict__ z, int n){
  int i = blockIdx.x * 256 + threadIdx.x;
  if (i >= n) return;
  int b = batch[i];
  float e = expf(s[i] - unflipf(mu[b]));
  s[i] = e;
  atomicAdd(&z[b], e);
}

__global__ __launch_bounds__(256) void k_sout(const float* __restrict__ s, const int* __restrict__ batch,
                                              const float* __restrict__ z, void* __restrict__ out, int n,
                                              const int* __restrict__ fl){
  int i = blockIdx.x * 256 + threadIdx.x;
  if (i >= n) return;
  const int isbf = *fl;
  float v = s[i] / z[batch[i]];
  if (isbf) ((u16*)out)[i] = ftobf(v);
  else      ((float*)out)[i] = v;
}

extern "C" void kernel_launch(void* const* d_in, const int* in_sizes, int n_in,
                              void* d_out, int out_size, void* d_ws, size_t ws_size,
                              hipStream_t stream){
  const void* x    = d_in[0];
  const int* ei    = (const int*)d_in[1];
  const int* batch = (const int*)d_in[2];
  const int* mask  = (const int*)d_in[3];
  const void* gw   = d_in[4];
  const void* gb   = d_in[5];
  const void* l1w  = d_in[6];
  const void* l1b  = d_in[7];
  const void* l2w  = d_in[8];
  const void* l2b  = d_in[9];

  const int N = in_sizes[2];
  const int E = in_sizes[1] / 2;
  const int D = 128;
  const int L = in_sizes[4] / (D * D);
  const int G = 1000;   // from reference; not derivable from sizes

  char* p = (char*)d_ws;
  u16*  Hb    = (u16*)p;   p += (size_t)N * D * sizeof(u16);
  u16*  Tb    = (u16*)p;   p += (size_t)N * D * sizeof(u16);
  u16*  Wf    = (u16*)p;   p += (size_t)(L + 1) * D * D * sizeof(u16);
  float* dinv = (float*)p; p += (size_t)N * sizeof(float);
  float* sbuf = (float*)p; p += (size_t)N * sizeof(float);
  int*  cnt   = (int*)p;   p += (size_t)N * sizeof(int);
  int*  boff  = (int*)p;   p += (size_t)(N + 1) * sizeof(int);
  int*  bsum  = (int*)p;   p += 1024 * sizeof(int);
  int*  eid   = (int*)p;   p += (size_t)E * sizeof(int);
  u32*  mu    = (u32*)p;   p += (size_t)G * sizeof(u32);
  float* z    = (float*)p; p += (size_t)G * sizeof(float);
  int*  flag  = (int*)p;   p += 256;

  const int* src  = ei;
  const int* dstp = ei + E;

  hipMemsetAsync(cnt, 0, (size_t)N * sizeof(int), stream);
  hipMemsetAsync(mu, 0, (size_t)G * sizeof(u32), stream);
  hipMemsetAsync(z, 0, (size_t)G * sizeof(float), stream);

  const int nb1 = (N + 255) / 256;
  const int mmg = (N + 63) / 64;
  const int ndg = (N + 3) / 4;
  const int n8  = N * D / 8;

  k_detect<<<1, 256, 0, stream>>>((const u32*)gw, 4096, flag);
  k_wprep<<<L + 1, 256, 0, stream>>>(gw, l1w, Wf, L, flag);
  k_cvt<<<(n8 + 255) / 256, 256, 0, stream>>>(x, Hb, n8, flag);

  k_count<<<(E + 255) / 256, 256, 0, stream>>>(dstp, cnt, E);
  k_scan1<<<nb1, 256, 0, stream>>>(cnt, boff, bsum, N);
  k_scan2<<<1, 512, 0, stream>>>(bsum, nb1);
  k_scan3<<<nb1, 256, 0, stream>>>(boff, bsum, N, E);
  k_dinv<<<nb1, 256, 0, stream>>>(cnt, dinv, N);     // before k_fill destroys cnt
  k_fill<<<(E + 255) / 256, 256, 0, stream>>>(src, dstp, cnt, boff, eid, E);

  for (int l = 0; l < L; ++l){
    k_mm<<<mmg, 256, 0, stream>>>(Hb, Wf + (size_t)l * D * D, nullptr, Tb, N, flag);
    k_gather<<<ndg, 256, 0, stream>>>(Tb, boff, eid, dinv, gb, l, Hb, N, (l < L - 1) ? 1 : 0, flag);
  }
  k_mm<<<mmg, 256, 0, stream>>>(Hb, Wf + (size_t)L * D * D, l1b, Tb, N, flag);
  k_score<<<ndg, 256, 0, stream>>>(Tb, l2w, l2b, mask, sbuf, N, flag);
  k_smax<<<nb1, 256, 0, stream>>>(sbuf, batch, mu, N);
  k_sexp<<<nb1, 256, 0, stream>>>(sbuf, batch, mu, z, N);
  k_sout<<<nb1, 256, 0, stream>>>(sbuf, batch, z, d_out, N, flag);
}

// Round 4
// 543.675 us; speedup vs baseline: 8.2068x; 1.1564x over previous
//
#include <hip/hip_runtime.h>
#include <hip/hip_bf16.h>

typedef unsigned int u32;
typedef unsigned short u16;
typedef __attribute__((ext_vector_type(8))) short bf16x8;
typedef __attribute__((ext_vector_type(4))) float f32x4;

__device__ __forceinline__ float u16tof(u16 u){ return __uint_as_float(((u32)u) << 16); }
__device__ __forceinline__ u16 ftobf(float f){
  u32 b = __float_as_uint(f);
  return (u16)((b + 0x7FFFu + ((b >> 16) & 1u)) >> 16);
}
__device__ __forceinline__ float ldf(const void* p, int i, int isbf){
  return isbf ? u16tof(((const u16*)p)[i]) : ((const float*)p)[i];
}
__device__ __forceinline__ u32 flipf(float x){
  u32 b = __float_as_uint(x);
  return (b & 0x80000000u) ? ~b : (b | 0x80000000u);
}
__device__ __forceinline__ float unflipf(u32 u){
  return (u & 0x80000000u) ? __uint_as_float(u & 0x7fffffffu) : __uint_as_float(~u);
}

// ---- dtype detect: bits[7:14] of each word are an exponent field iff bf16-packed ----
__global__ __launch_bounds__(256) void k_detect(const u32* __restrict__ w, int nwords, int* __restrict__ flag){
  __shared__ int cnt;
  if (threadIdx.x == 0) cnt = 0;
  __syncthreads();
  int local = 0;
  for (int i = threadIdx.x; i < nwords; i += 256){
    u32 e = (w[i] >> 7) & 0xFFu;
    if (e >= 100u && e < 127u) local++;
  }
  atomicAdd(&cnt, local);
  __syncthreads();
  if (threadIdx.x == 0) *flag = (cnt > nwords / 2) ? 1 : 0;
}

// ---- weight prep: fragment-ordered bf16 Wf for gw[0..L-1] and l1w ----
// Wf[b][((t*4+ks)*64+lane)*8 + j] = W_b[k][n],  k=ks*32+(lane>>4)*8+j, n=t*16+(lane&15)
__global__ __launch_bounds__(256) void k_wprep(const void* __restrict__ gw, const void* __restrict__ l1w,
                                               u16* __restrict__ Wf, int L, const int* __restrict__ fl){
  const int isbf = *fl;
  const int b = blockIdx.x;
  const void* src = (b < L) ? gw : l1w;
  const int sbase = (b < L) ? b * 16384 : 0;
  u16* dst = Wf + (size_t)b * 16384;
  for (int g = threadIdx.x; g < 2048; g += 256){
    const int t = g >> 8, ks = (g >> 6) & 3, lane = g & 63;
    const int n = t * 16 + (lane & 15);
    const int k0 = ks * 32 + ((lane >> 4) << 3);
    u16* d = dst + (size_t)g * 8;
    #pragma unroll
    for (int j = 0; j < 8; ++j){
      d[j] = ftobf(ldf(src, sbase + (k0 + j) * 128 + n, isbf));
    }
  }
}

// ---- x -> bf16 Hb (fp32 path only; bf16 path reads x directly in k_mm) ----
__global__ __launch_bounds__(256) void k_cvt(const void* __restrict__ in, u16* __restrict__ out, int n8,
                                             const int* __restrict__ fl){
  if (*fl) return;
  int i = blockIdx.x * 256 + threadIdx.x;
  if (i >= n8) return;
  const float4 a = ((const float4*)in)[i * 2];
  const float4 b = ((const float4*)in)[i * 2 + 1];
  u16* o = out + (size_t)i * 8;
  o[0] = ftobf(a.x); o[1] = ftobf(a.y); o[2] = ftobf(a.z); o[3] = ftobf(a.w);
  o[4] = ftobf(b.x); o[5] = ftobf(b.y); o[6] = ftobf(b.z); o[7] = ftobf(b.w);
}

// ---- degree count over dst ----
__global__ __launch_bounds__(256) void k_count(const int* __restrict__ dst, int* __restrict__ cnt, int nE){
  int i = blockIdx.x * 256 + threadIdx.x;
  if (i < nE) atomicAdd(&cnt[dst[i]], 1);
}

__global__ __launch_bounds__(256) void k_dinv(const int* __restrict__ cnt, float* __restrict__ dinv, int n){
  int i = blockIdx.x * 256 + threadIdx.x;
  if (i < n) dinv[i] = rsqrtf((float)cnt[i] + 1.0f);
}

// ---- exclusive scan of cnt -> boff ----
__global__ __launch_bounds__(256) void k_scan1(const int* __restrict__ cnt, int* __restrict__ boff,
                                               int* __restrict__ bsum, int n){
  __shared__ int sm[256];
  int t = threadIdx.x;
  int i = blockIdx.x * 256 + t;
  int v = (i < n) ? cnt[i] : 0;
  sm[t] = v; __syncthreads();
  for (int off = 1; off < 256; off <<= 1){
    int add = (t >= off) ? sm[t - off] : 0;
    __syncthreads();
    sm[t] += add;
    __syncthreads();
  }
  if (i < n) boff[i] = sm[t] - v;
  if (t == 255) bsum[blockIdx.x] = sm[255];
}

__global__ __launch_bounds__(512) void k_scan2(int* __restrict__ bsum, int nb){
  __shared__ int sm[512];
  int t = threadIdx.x;
  int v = (t < nb) ? bsum[t] : 0;
  sm[t] = v; __syncthreads();
  for (int off = 1; off < 512; off <<= 1){
    int add = (t >= off) ? sm[t - off] : 0;
    __syncthreads();
    sm[t] += add;
    __syncthreads();
  }
  if (t < nb) bsum[t] = sm[t] - v;
}

__global__ __launch_bounds__(256) void k_scan3(int* __restrict__ boff, const int* __restrict__ bsum, int n, int nE){
  int i = blockIdx.x * 256 + threadIdx.x;
  if (i < n) boff[i] += bsum[blockIdx.x];
  if (i == 0) boff[n] = nE;
}

// ---- counting-sort edges by dst: eid[slot] = src ----
__global__ __launch_bounds__(256) void k_fill(const int* __restrict__ src, const int* __restrict__ dst,
                                              int* __restrict__ cnt, const int* __restrict__ boff,
                                              int* __restrict__ eid, int nE){
  int e = blockIdx.x * 256 + threadIdx.x;
  if (e >= nE) return;
  int d = dst[e];
  int old = atomicSub(&cnt[d], 1);
  eid[boff[d] + old - 1] = src[e];
}

// ---- GCN matmul: Ts[n,128] = (A[n,128] @ W) * dinv[row], bf16 out ----
__global__ __launch_bounds__(256) void k_mm(const void* __restrict__ X, const u16* __restrict__ Hb, int use_x,
                                            const u16* __restrict__ Wf, const float* __restrict__ dinv,
                                            u16* __restrict__ T, int n, const int* __restrict__ fl){
  const int isbf = *fl;
  const u16* A = (use_x && isbf) ? (const u16*)X : Hb;
  const int wave = threadIdx.x >> 6, lane = threadIdx.x & 63;
  const int m0 = blockIdx.x * 64 + wave * 16;
  int arow = m0 + (lane & 15); if (arow > n - 1) arow = n - 1;
  const u16* aptr = A + (size_t)arow * 128 + ((lane >> 4) << 3);

  f32x4 acc[8];
  #pragma unroll
  for (int t = 0; t < 8; ++t) acc[t] = (f32x4){0.f, 0.f, 0.f, 0.f};

  #pragma unroll
  for (int ks = 0; ks < 4; ++ks){
    const bf16x8 a = *(const bf16x8*)(aptr + ks * 32);
    #pragma unroll
    for (int t = 0; t < 8; ++t){
      const bf16x8 b = *(const bf16x8*)(Wf + (size_t)(((t * 4 + ks) * 64 + lane) * 8));
      acc[t] = __builtin_amdgcn_mfma_f32_16x16x32_bf16(a, b, acc[t], 0, 0, 0);
    }
  }

  const int quad = lane >> 4, col0 = lane & 15;
  float dv[4];
  #pragma unroll
  for (int r = 0; r < 4; ++r){
    const int row = m0 + quad * 4 + r;
    dv[r] = (row < n) ? dinv[row] : 0.f;
  }
  #pragma unroll
  for (int t = 0; t < 8; ++t){
    const int col = t * 16 + col0;
    #pragma unroll
    for (int r = 0; r < 4; ++r){
      const int row = m0 + quad * 4 + r;
      if (row < n) T[(size_t)row * 128 + col] = ftobf(acc[t][r] * dv[r]);
    }
  }
}

// ---- fused head: s = relu(A@W1 + b1).w2 + b2, mask, write s, atomicMax per-graph ----
__global__ __launch_bounds__(256) void k_mmhead(const u16* __restrict__ Hb, const u16* __restrict__ Wf,
                                                const void* __restrict__ b1, const void* __restrict__ w2,
                                                const void* __restrict__ b2, const int* __restrict__ mask,
                                                const int* __restrict__ batch, float* __restrict__ s,
                                                u32* __restrict__ mu, int n, const int* __restrict__ fl){
  const int isbf = *fl;
  const int wave = threadIdx.x >> 6, lane = threadIdx.x & 63;
  const int m0 = blockIdx.x * 64 + wave * 16;
  int arow = m0 + (lane & 15); if (arow > n - 1) arow = n - 1;
  const u16* aptr = Hb + (size_t)arow * 128 + ((lane >> 4) << 3);

  f32x4 acc[8];
  #pragma unroll
  for (int t = 0; t < 8; ++t) acc[t] = (f32x4){0.f, 0.f, 0.f, 0.f};

  #pragma unroll
  for (int ks = 0; ks < 4; ++ks){
    const bf16x8 a = *(const bf16x8*)(aptr + ks * 32);
    #pragma unroll
    for (int t = 0; t < 8; ++t){
      const bf16x8 b = *(const bf16x8*)(Wf + (size_t)(((t * 4 + ks) * 64 + lane) * 8));
      acc[t] = __builtin_amdgcn_mfma_f32_16x16x32_bf16(a, b, acc[t], 0, 0, 0);
    }
  }

  const int quad = lane >> 4, col0 = lane & 15;
  float rs0 = 0.f, rs1 = 0.f, rs2 = 0.f, rs3 = 0.f;
  #pragma unroll
  for (int t = 0; t < 8; ++t){
    const int col = t * 16 + col0;
    const float bv = ldf(b1, col, isbf);
    const float wv = ldf(w2, col, isbf);
    rs0 = fmaf(fmaxf(acc[t][0] + bv, 0.f), wv, rs0);
    rs1 = fmaf(fmaxf(acc[t][1] + bv, 0.f), wv, rs1);
    rs2 = fmaf(fmaxf(acc[t][2] + bv, 0.f), wv, rs2);
    rs3 = fmaf(fmaxf(acc[t][3] + bv, 0.f), wv, rs3);
  }
  #pragma unroll
  for (int k = 1; k < 16; k <<= 1){
    rs0 += __shfl_xor(rs0, k);
    rs1 += __shfl_xor(rs1, k);
    rs2 += __shfl_xor(rs2, k);
    rs3 += __shfl_xor(rs3, k);
  }
  if (col0 < 4){
    const int row = m0 + quad * 4 + col0;
    if (row < n){
      float sc = (col0 == 0 ? rs0 : col0 == 1 ? rs1 : col0 == 2 ? rs2 : rs3) + ldf(b2, 0, isbf);
      if (mask[row] == 0) sc = -1e9f;
      s[row] = sc;
      atomicMax(&mu[batch[row]], flipf(sc));
    }
  }
}

// ---- H[i] = (sum_{e->i} Ts[src] + Ts[i]) * dinv[i] + b[layer]; opt relu ----
__global__ __launch_bounds__(256) void k_gather(const u16* __restrict__ T, const int* __restrict__ boff,
                                                const int* __restrict__ eid, const float* __restrict__ dinv,
                                                const void* __restrict__ bias, int layer,
                                                u16* __restrict__ H, int n, int relu,
                                                const int* __restrict__ fl){
  const int node = blockIdx.x * 4 + (threadIdx.x >> 6);
  if (node >= n) return;
  const int isbf = *fl;
  const int lane = threadIdx.x & 63;
  const float di = dinv[node];
  const u32 sv = ((const u32*)(T + (size_t)node * 128))[lane];
  float acc0 = u16tof((u16)(sv & 0xffff));
  float acc1 = u16tof((u16)(sv >> 16));
  const int b0 = boff[node], b1 = boff[node + 1];
  int j = b0;
  for (; j + 4 <= b1; j += 4){
    const int s0 = eid[j], s1 = eid[j + 1], s2 = eid[j + 2], s3 = eid[j + 3];
    const u32 v0 = ((const u32*)(T + (size_t)s0 * 128))[lane];
    const u32 v1 = ((const u32*)(T + (size_t)s1 * 128))[lane];
    const u32 v2 = ((const u32*)(T + (size_t)s2 * 128))[lane];
    const u32 v3 = ((const u32*)(T + (size_t)s3 * 128))[lane];
    acc0 += (u16tof((u16)(v0 & 0xffff)) + u16tof((u16)(v1 & 0xffff)))
          + (u16tof((u16)(v2 & 0xffff)) + u16tof((u16)(v3 & 0xffff)));
    acc1 += (u16tof((u16)(v0 >> 16)) + u16tof((u16)(v1 >> 16)))
          + (u16tof((u16)(v2 >> 16)) + u16tof((u16)(v3 >> 16)));
  }
  for (; j < b1; ++j){
    const u32 v = ((const u32*)(T + (size_t)eid[j] * 128))[lane];
    acc0 += u16tof((u16)(v & 0xffff));
    acc1 += u16tof((u16)(v >> 16));
  }
  const int bb = layer * 128 + (lane << 1);
  float h0 = fmaf(acc0, di, ldf(bias, bb, isbf));
  float h1 = fmaf(acc1, di, ldf(bias, bb + 1, isbf));
  if (relu){ h0 = fmaxf(h0, 0.f); h1 = fmaxf(h1, 0.f); }
  ((u32*)(H + (size_t)node * 128))[lane] = (u32)ftobf(h0) | ((u32)ftobf(h1) << 16);
}

// ---- segment softmax (max already in mu) ----
__global__ __launch_bounds__(256) void k_sexp(float* __restrict__ s, const int* __restrict__ batch,
                                              const u32* __restrict__ mu, float* __restrict__ z, int n){
  int i = blockIdx.x * 256 + threadIdx.x;
  if (i >= n) return;
  int b = batch[i];
  float e = expf(s[i] - unflipf(mu[b]));
  s[i] = e;
  atomicAdd(&z[b], e);
}

__global__ __launch_bounds__(256) void k_sout(const float* __restrict__ s, const int* __restrict__ batch,
                                              const float* __restrict__ z, void* __restrict__ out, int n,
                                              const int* __restrict__ fl){
  int i = blockIdx.x * 256 + threadIdx.x;
  if (i >= n) return;
  float v = s[i] / z[batch[i]];
  if (*fl) ((u16*)out)[i] = ftobf(v);
  else     ((float*)out)[i] = v;
}

extern "C" void kernel_launch(void* const* d_in, const int* in_sizes, int n_in,
                              void* d_out, int out_size, void* d_ws, size_t ws_size,
                              hipStream_t stream){
  const void* x    = d_in[0];
  const int* ei    = (const int*)d_in[1];
  const int* batch = (const int*)d_in[2];
  const int* mask  = (const int*)d_in[3];
  const void* gw   = d_in[4];
  const void* gb   = d_in[5];
  const void* l1w  = d_in[6];
  const void* l1b  = d_in[7];
  const void* l2w  = d_in[8];
  const void* l2b  = d_in[9];

  const int N = in_sizes[2];
  const int E = in_sizes[1] / 2;
  const int D = 128;
  const int L = in_sizes[4] / (D * D);
  const int G = 1000;   // from reference; not derivable from sizes

  char* p = (char*)d_ws;
  u16*  Hb    = (u16*)p;   p += (size_t)N * D * sizeof(u16);
  u16*  Tb    = (u16*)p;   p += (size_t)N * D * sizeof(u16);
  u16*  Wf    = (u16*)p;   p += (size_t)(L + 1) * D * D * sizeof(u16);
  float* dinv = (float*)p; p += (size_t)N * sizeof(float);
  float* sbuf = (float*)p; p += (size_t)N * sizeof(float);
  int*  cnt   = (int*)p;   p += (size_t)N * sizeof(int);
  int*  boff  = (int*)p;   p += (size_t)(N + 1) * sizeof(int);
  int*  bsum  = (int*)p;   p += 1024 * sizeof(int);
  int*  eid   = (int*)p;   p += (size_t)E * sizeof(int);
  u32*  mu    = (u32*)p;   p += (size_t)G * sizeof(u32);
  float* z    = (float*)p; p += (size_t)G * sizeof(float);
  int*  flag  = (int*)p;   p += 256;

  const int* src  = ei;
  const int* dstp = ei + E;

  hipMemsetAsync(cnt, 0, (size_t)N * sizeof(int), stream);
  hipMemsetAsync(mu, 0, (size_t)G * sizeof(u32), stream);
  hipMemsetAsync(z, 0, (size_t)G * sizeof(float), stream);

  const int nb1 = (N + 255) / 256;
  const int mmg = (N + 63) / 64;
  const int ndg = (N + 3) / 4;
  const int n8  = N * D / 8;

  k_detect<<<1, 256, 0, stream>>>((const u32*)gw, 4096, flag);
  k_wprep<<<L + 1, 256, 0, stream>>>(gw, l1w, Wf, L, flag);
  k_cvt<<<(n8 + 255) / 256, 256, 0, stream>>>(x, Hb, n8, flag);

  k_count<<<(E + 255) / 256, 256, 0, stream>>>(dstp, cnt, E);
  k_scan1<<<nb1, 256, 0, stream>>>(cnt, boff, bsum, N);
  k_scan2<<<1, 512, 0, stream>>>(bsum, nb1);
  k_scan3<<<nb1, 256, 0, stream>>>(boff, bsum, N, E);
  k_dinv<<<nb1, 256, 0, stream>>>(cnt, dinv, N);     // before k_fill destroys cnt
  k_fill<<<(E + 255) / 256, 256, 0, stream>>>(src, dstp, cnt, boff, eid, E);

  for (int l = 0; l < L; ++l){
    k_mm<<<mmg, 256, 0, stream>>>(x, Hb, (l == 0) ? 1 : 0, Wf + (size_t)l * D * D, dinv, Tb, N, flag);
    k_gather<<<ndg, 256, 0, stream>>>(Tb, boff, eid, dinv, gb, l, Hb, N, (l < L - 1) ? 1 : 0, flag);
  }
  k_mmhead<<<mmg, 256, 0, stream>>>(Hb, Wf + (size_t)L * D * D, l1b, l2w, l2b, mask, batch, sbuf, mu, N, flag);
  k_sexp<<<nb1, 256, 0, stream>>>(sbuf, batch, mu, z, N);
  k_sout<<<nb1, 256, 0, stream>>>(sbuf, batch, z, d_out, N, flag);
}

// Round 5
// 421.493 us; speedup vs baseline: 10.5858x; 1.2899x over previous
//
#include <hip/hip_runtime.h>
#include <hip/hip_bf16.h>

typedef unsigned int u32;
typedef unsigned short u16;
typedef __attribute__((ext_vector_type(8))) short bf16x8;
typedef __attribute__((ext_vector_type(4))) float f32x4;

__device__ __forceinline__ float u16tof(u16 u){ return __uint_as_float(((u32)u) << 16); }
__device__ __forceinline__ u16 ftobf(float f){
  u32 b = __float_as_uint(f);
  return (u16)((b + 0x7FFFu + ((b >> 16) & 1u)) >> 16);
}
__device__ __forceinline__ float ldf(const void* p, int i, int isbf){
  return isbf ? u16tof(((const u16*)p)[i]) : ((const float*)p)[i];
}

// ---- dtype detect: bits[7:14] of each word are an exponent field iff bf16-packed ----
__global__ __launch_bounds__(256) void k_detect(const u32* __restrict__ w, int nwords, int* __restrict__ flag){
  __shared__ int cnt;
  if (threadIdx.x == 0) cnt = 0;
  __syncthreads();
  int local = 0;
  for (int i = threadIdx.x; i < nwords; i += 256){
    u32 e = (w[i] >> 7) & 0xFFu;
    if (e >= 100u && e < 127u) local++;
  }
  atomicAdd(&cnt, local);
  __syncthreads();
  if (threadIdx.x == 0) *flag = (cnt > nwords / 2) ? 1 : 0;
}

// ---- weight prep: fragment-ordered bf16 Wf for gw[0..L-1] and l1w ----
// Wf[b][((t*4+ks)*64+lane)*8 + j] = W_b[k][n],  k=ks*32+(lane>>4)*8+j, n=t*16+(lane&15)
__global__ __launch_bounds__(256) void k_wprep(const void* __restrict__ gw, const void* __restrict__ l1w,
                                               u16* __restrict__ Wf, int L, const int* __restrict__ fl){
  const int isbf = *fl;
  const int b = blockIdx.x;
  const void* src = (b < L) ? gw : l1w;
  const int sbase = (b < L) ? b * 16384 : 0;
  u16* dst = Wf + (size_t)b * 16384;
  for (int g = threadIdx.x; g < 2048; g += 256){
    const int t = g >> 8, ks = (g >> 6) & 3, lane = g & 63;
    const int n = t * 16 + (lane & 15);
    const int k0 = ks * 32 + ((lane >> 4) << 3);
    u16* d = dst + (size_t)g * 8;
    #pragma unroll
    for (int j = 0; j < 8; ++j){
      d[j] = ftobf(ldf(src, sbase + (k0 + j) * 128 + n, isbf));
    }
  }
}

// ---- x -> bf16 Hb (fp32 path only; bf16 path reads x directly in k_mm) ----
__global__ __launch_bounds__(256) void k_cvt(const void* __restrict__ in, u16* __restrict__ out, int n8,
                                             const int* __restrict__ fl){
  if (*fl) return;
  int i = blockIdx.x * 256 + threadIdx.x;
  if (i >= n8) return;
  const float4 a = ((const float4*)in)[i * 2];
  const float4 b = ((const float4*)in)[i * 2 + 1];
  u16* o = out + (size_t)i * 8;
  o[0] = ftobf(a.x); o[1] = ftobf(a.y); o[2] = ftobf(a.z); o[3] = ftobf(a.w);
  o[4] = ftobf(b.x); o[5] = ftobf(b.y); o[6] = ftobf(b.z); o[7] = ftobf(b.w);
}

// ---- degree count over dst ----
__global__ __launch_bounds__(256) void k_count(const int* __restrict__ dst, int* __restrict__ cnt, int nE){
  int i = blockIdx.x * 256 + threadIdx.x;
  if (i < nE) atomicAdd(&cnt[dst[i]], 1);
}

// ---- exclusive scan of cnt -> boff ; also dinv = rsqrt(cnt+1) ----
__global__ __launch_bounds__(256) void k_scan1(const int* __restrict__ cnt, int* __restrict__ boff,
                                               int* __restrict__ bsum, float* __restrict__ dinv, int n){
  __shared__ int sm[256];
  int t = threadIdx.x;
  int i = blockIdx.x * 256 + t;
  int v = (i < n) ? cnt[i] : 0;
  if (i < n) dinv[i] = rsqrtf((float)v + 1.0f);
  sm[t] = v; __syncthreads();
  for (int off = 1; off < 256; off <<= 1){
    int add = (t >= off) ? sm[t - off] : 0;
    __syncthreads();
    sm[t] += add;
    __syncthreads();
  }
  if (i < n) boff[i] = sm[t] - v;
  if (t == 255) bsum[blockIdx.x] = sm[255];
}

__global__ __launch_bounds__(512) void k_scan2(int* __restrict__ bsum, int nb){
  __shared__ int sm[512];
  int t = threadIdx.x;
  int v = (t < nb) ? bsum[t] : 0;
  sm[t] = v; __syncthreads();
  for (int off = 1; off < 512; off <<= 1){
    int add = (t >= off) ? sm[t - off] : 0;
    __syncthreads();
    sm[t] += add;
    __syncthreads();
  }
  if (t < nb) bsum[t] = sm[t] - v;
}

__global__ __launch_bounds__(256) void k_scan3(int* __restrict__ boff, const int* __restrict__ bsum, int n, int nE){
  int i = blockIdx.x * 256 + threadIdx.x;
  if (i < n) boff[i] += bsum[blockIdx.x];
  if (i == 0) boff[n] = nE;
}

// ---- counting-sort edges by dst: eid[slot] = src ----
__global__ __launch_bounds__(256) void k_fill(const int* __restrict__ src, const int* __restrict__ dst,
                                              int* __restrict__ cnt, const int* __restrict__ boff,
                                              int* __restrict__ eid, int nE){
  int e = blockIdx.x * 256 + threadIdx.x;
  if (e >= nE) return;
  int d = dst[e];
  int old = atomicSub(&cnt[d], 1);
  eid[boff[d] + old - 1] = src[e];
}

// ---- GCN matmul: Ts[n,128] = (A[n,128] @ W) * dinv[row], bf16 out ----
__global__ __launch_bounds__(256) void k_mm(const void* __restrict__ X, const u16* __restrict__ Hb, int use_x,
                                            const u16* __restrict__ Wf, const float* __restrict__ dinv,
                                            u16* __restrict__ T, int n, const int* __restrict__ fl){
  const int isbf = *fl;
  const u16* A = (use_x && isbf) ? (const u16*)X : Hb;
  const int wave = threadIdx.x >> 6, lane = threadIdx.x & 63;
  const int m0 = blockIdx.x * 64 + wave * 16;
  int arow = m0 + (lane & 15); if (arow > n - 1) arow = n - 1;
  const u16* aptr = A + (size_t)arow * 128 + ((lane >> 4) << 3);

  f32x4 acc[8];
  #pragma unroll
  for (int t = 0; t < 8; ++t) acc[t] = (f32x4){0.f, 0.f, 0.f, 0.f};

  #pragma unroll
  for (int ks = 0; ks < 4; ++ks){
    const bf16x8 a = *(const bf16x8*)(aptr + ks * 32);
    #pragma unroll
    for (int t = 0; t < 8; ++t){
      const bf16x8 b = *(const bf16x8*)(Wf + (size_t)(((t * 4 + ks) * 64 + lane) * 8));
      acc[t] = __builtin_amdgcn_mfma_f32_16x16x32_bf16(a, b, acc[t], 0, 0, 0);
    }
  }

  const int quad = lane >> 4, col0 = lane & 15;
  float dv[4];
  #pragma unroll
  for (int r = 0; r < 4; ++r){
    const int row = m0 + quad * 4 + r;
    dv[r] = (row < n) ? dinv[row] : 0.f;
  }
  #pragma unroll
  for (int t = 0; t < 8; ++t){
    const int col = t * 16 + col0;
    #pragma unroll
    for (int r = 0; r < 4; ++r){
      const int row = m0 + quad * 4 + r;
      if (row < n) T[(size_t)row * 128 + col] = ftobf(acc[t][r] * dv[r]);
    }
  }
}

// ---- fused head: s = relu(A@W1 + b1).w2 + b2, mask, write s (NO atomics) ----
__global__ __launch_bounds__(256) void k_mmhead(const u16* __restrict__ Hb, const u16* __restrict__ Wf,
                                                const void* __restrict__ b1, const void* __restrict__ w2,
                                                const void* __restrict__ b2, const int* __restrict__ mask,
                                                float* __restrict__ s, int n, const int* __restrict__ fl){
  const int isbf = *fl;
  const int wave = threadIdx.x >> 6, lane = threadIdx.x & 63;
  const int m0 = blockIdx.x * 64 + wave * 16;
  int arow = m0 + (lane & 15); if (arow > n - 1) arow = n - 1;
  const u16* aptr = Hb + (size_t)arow * 128 + ((lane >> 4) << 3);

  f32x4 acc[8];
  #pragma unroll
  for (int t = 0; t < 8; ++t) acc[t] = (f32x4){0.f, 0.f, 0.f, 0.f};

  #pragma unroll
  for (int ks = 0; ks < 4; ++ks){
    const bf16x8 a = *(const bf16x8*)(aptr + ks * 32);
    #pragma unroll
    for (int t = 0; t < 8; ++t){
      const bf16x8 b = *(const bf16x8*)(Wf + (size_t)(((t * 4 + ks) * 64 + lane) * 8));
      acc[t] = __builtin_amdgcn_mfma_f32_16x16x32_bf16(a, b, acc[t], 0, 0, 0);
    }
  }

  const int quad = lane >> 4, col0 = lane & 15;
  float rs0 = 0.f, rs1 = 0.f, rs2 = 0.f, rs3 = 0.f;
  #pragma unroll
  for (int t = 0; t < 8; ++t){
    const int col = t * 16 + col0;
    const float bv = ldf(b1, col, isbf);
    const float wv = ldf(w2, col, isbf);
    rs0 = fmaf(fmaxf(acc[t][0] + bv, 0.f), wv, rs0);
    rs1 = fmaf(fmaxf(acc[t][1] + bv, 0.f), wv, rs1);
    rs2 = fmaf(fmaxf(acc[t][2] + bv, 0.f), wv, rs2);
    rs3 = fmaf(fmaxf(acc[t][3] + bv, 0.f), wv, rs3);
  }
  #pragma unroll
  for (int k = 1; k < 16; k <<= 1){
    rs0 += __shfl_xor(rs0, k);
    rs1 += __shfl_xor(rs1, k);
    rs2 += __shfl_xor(rs2, k);
    rs3 += __shfl_xor(rs3, k);
  }
  if (col0 < 4){
    const int row = m0 + quad * 4 + col0;
    if (row < n){
      float sc = (col0 == 0 ? rs0 : col0 == 1 ? rs1 : col0 == 2 ? rs2 : rs3) + ldf(b2, 0, isbf);
      if (mask[row] == 0) sc = -1e9f;
      s[row] = sc;
    }
  }
}

// ---- H[i] = (sum_{e->i} Ts[src] + Ts[i]) * dinv[i] + b[layer]; opt relu ----
__global__ __launch_bounds__(256) void k_gather(const u16* __restrict__ T, const int* __restrict__ boff,
                                                const int* __restrict__ eid, const float* __restrict__ dinv,
                                                const void* __restrict__ bias, int layer,
                                                u16* __restrict__ H, int n, int relu,
                                                const int* __restrict__ fl){
  const int node = blockIdx.x * 4 + (threadIdx.x >> 6);
  if (node >= n) return;
  const int isbf = *fl;
  const int lane = threadIdx.x & 63;
  const float di = dinv[node];
  const u32 sv = ((const u32*)(T + (size_t)node * 128))[lane];
  float acc0 = u16tof((u16)(sv & 0xffff));
  float acc1 = u16tof((u16)(sv >> 16));
  const int b0 = boff[node], b1 = boff[node + 1];
  int j = b0;
  for (; j + 4 <= b1; j += 4){
    const int s0 = eid[j], s1 = eid[j + 1], s2 = eid[j + 2], s3 = eid[j + 3];
    const u32 v0 = ((const u32*)(T + (size_t)s0 * 128))[lane];
    const u32 v1 = ((const u32*)(T + (size_t)s1 * 128))[lane];
    const u32 v2 = ((const u32*)(T + (size_t)s2 * 128))[lane];
    const u32 v3 = ((const u32*)(T + (size_t)s3 * 128))[lane];
    acc0 += (u16tof((u16)(v0 & 0xffff)) + u16tof((u16)(v1 & 0xffff)))
          + (u16tof((u16)(v2 & 0xffff)) + u16tof((u16)(v3 & 0xffff)));
    acc1 += (u16tof((u16)(v0 >> 16)) + u16tof((u16)(v1 >> 16)))
          + (u16tof((u16)(v2 >> 16)) + u16tof((u16)(v3 >> 16)));
  }
  for (; j < b1; ++j){
    const u32 v = ((const u32*)(T + (size_t)eid[j] * 128))[lane];
    acc0 += u16tof((u16)(v & 0xffff));
    acc1 += u16tof((u16)(v >> 16));
  }
  const int bb = layer * 128 + (lane << 1);
  float h0 = fmaf(acc0, di, ldf(bias, bb, isbf));
  float h1 = fmaf(acc1, di, ldf(bias, bb + 1, isbf));
  if (relu){ h0 = fmaxf(h0, 0.f); h1 = fmaxf(h1, 0.f); }
  ((u32*)(H + (size_t)node * 128))[lane] = (u32)ftobf(h0) | ((u32)ftobf(h1) << 16);
}

// ---- goff[g] = first node index of graph g (batch sorted); goff[G] = N ----
__global__ __launch_bounds__(256) void k_goff(const int* __restrict__ batch, int* __restrict__ goff,
                                              int n, int G){
  int i = blockIdx.x * 256 + threadIdx.x;
  if (i >= n) return;
  int b = batch[i];
  int prev = (i == 0) ? -1 : batch[i - 1];
  for (int g = prev + 1; g <= b; ++g) goff[g] = i;
  if (i == n - 1){
    for (int g = b + 1; g <= G; ++g) goff[g] = n;
  }
}

// ---- per-graph softmax: wave per graph, contiguous segment [goff[g], goff[g+1]) ----
__global__ __launch_bounds__(256) void k_gsm(const float* __restrict__ s, const int* __restrict__ goff,
                                             void* __restrict__ out, int G, const int* __restrict__ fl){
  const int g = blockIdx.x * 4 + (threadIdx.x >> 6);
  if (g >= G) return;
  const int lane = threadIdx.x & 63;
  const int i0 = goff[g], i1 = goff[g + 1];
  if (i0 >= i1) return;
  float m = -3.4e38f;
  for (int j = i0 + lane; j < i1; j += 64) m = fmaxf(m, s[j]);
  #pragma unroll
  for (int k = 32; k; k >>= 1) m = fmaxf(m, __shfl_xor(m, k));
  float zz = 0.f;
  for (int j = i0 + lane; j < i1; j += 64) zz += expf(s[j] - m);
  #pragma unroll
  for (int k = 32; k; k >>= 1) zz += __shfl_xor(zz, k);
  const float rz = 1.f / zz;
  const int isbf = *fl;
  for (int j = i0 + lane; j < i1; j += 64){
    const float v = expf(s[j] - m) * rz;
    if (isbf) ((u16*)out)[j] = ftobf(v);
    else      ((float*)out)[j] = v;
  }
}

extern "C" void kernel_launch(void* const* d_in, const int* in_sizes, int n_in,
                              void* d_out, int out_size, void* d_ws, size_t ws_size,
                              hipStream_t stream){
  const void* x    = d_in[0];
  const int* ei    = (const int*)d_in[1];
  const int* batch = (const int*)d_in[2];
  const int* mask  = (const int*)d_in[3];
  const void* gw   = d_in[4];
  const void* gb   = d_in[5];
  const void* l1w  = d_in[6];
  const void* l1b  = d_in[7];
  const void* l2w  = d_in[8];
  const void* l2b  = d_in[9];

  const int N = in_sizes[2];
  const int E = in_sizes[1] / 2;
  const int D = 128;
  const int L = in_sizes[4] / (D * D);
  const int G = 1000;   // from reference; not derivable from sizes

  char* p = (char*)d_ws;
  u16*  Hb    = (u16*)p;   p += (size_t)N * D * sizeof(u16);
  u16*  Tb    = (u16*)p;   p += (size_t)N * D * sizeof(u16);
  u16*  Wf    = (u16*)p;   p += (size_t)(L + 1) * D * D * sizeof(u16);
  float* dinv = (float*)p; p += (size_t)N * sizeof(float);
  float* sbuf = (float*)p; p += (size_t)N * sizeof(float);
  int*  cnt   = (int*)p;   p += (size_t)N * sizeof(int);
  int*  boff  = (int*)p;   p += (size_t)(N + 1) * sizeof(int);
  int*  bsum  = (int*)p;   p += 1024 * sizeof(int);
  int*  eid   = (int*)p;   p += (size_t)E * sizeof(int);
  int*  goff  = (int*)p;   p += (size_t)(G + 1) * sizeof(int);
  int*  flag  = (int*)p;   p += 256;

  const int* src  = ei;
  const int* dstp = ei + E;

  hipMemsetAsync(cnt, 0, (size_t)N * sizeof(int), stream);

  const int nb1 = (N + 255) / 256;
  const int mmg = (N + 63) / 64;
  const int ndg = (N + 3) / 4;
  const int n8  = N * D / 8;

  k_detect<<<1, 256, 0, stream>>>((const u32*)gw, 4096, flag);
  k_wprep<<<L + 1, 256, 0, stream>>>(gw, l1w, Wf, L, flag);
  k_cvt<<<(n8 + 255) / 256, 256, 0, stream>>>(x, Hb, n8, flag);

  k_count<<<(E + 255) / 256, 256, 0, stream>>>(dstp, cnt, E);
  k_scan1<<<nb1, 256, 0, stream>>>(cnt, boff, bsum, dinv, N);
  k_scan2<<<1, 512, 0, stream>>>(bsum, nb1);
  k_scan3<<<nb1, 256, 0, stream>>>(boff, bsum, N, E);
  k_fill<<<(E + 255) / 256, 256, 0, stream>>>(src, dstp, cnt, boff, eid, E);
  k_goff<<<nb1, 256, 0, stream>>>(batch, goff, N, G);

  for (int l = 0; l < L; ++l){
    k_mm<<<mmg, 256, 0, stream>>>(x, Hb, (l == 0) ? 1 : 0, Wf + (size_t)l * D * D, dinv, Tb, N, flag);
    k_gather<<<ndg, 256, 0, stream>>>(Tb, boff, eid, dinv, gb, l, Hb, N, (l < L - 1) ? 1 : 0, flag);
  }
  k_mmhead<<<mmg, 256, 0, stream>>>(Hb, Wf + (size_t)L * D * D, l1b, l2w, l2b, mask, sbuf, N, flag);
  k_gsm<<<(G + 3) / 4, 256, 0, stream>>>(sbuf, goff, d_out, G, flag);
}

// Round 6
// 399.773 us; speedup vs baseline: 11.1609x; 1.0543x over previous
//
#include <hip/hip_runtime.h>
#include <hip/hip_bf16.h>

typedef unsigned int u32;
typedef unsigned short u16;
typedef __attribute__((ext_vector_type(8))) short bf16x8;
typedef __attribute__((ext_vector_type(4))) float f32x4;

__device__ __forceinline__ float u16tof(u16 u){ return __uint_as_float(((u32)u) << 16); }
__device__ __forceinline__ float lo16(u32 v){ return __uint_as_float(v << 16); }
__device__ __forceinline__ float hi16(u32 v){ return __uint_as_float(v & 0xffff0000u); }
__device__ __forceinline__ u16 ftobf(float f){
  u32 b = __float_as_uint(f);
  return (u16)((b + 0x7FFFu + ((b >> 16) & 1u)) >> 16);
}
__device__ __forceinline__ u32 pack2(float a, float b){
  return (u32)ftobf(a) | ((u32)ftobf(b) << 16);
}
__device__ __forceinline__ float ldf(const void* p, int i, int isbf){
  return isbf ? u16tof(((const u16*)p)[i]) : ((const float*)p)[i];
}

// ---- weight prep (self-detecting dtype): fragment-ordered bf16 Wf for gw[0..L-1] and l1w ----
// Wf[b][((t*4+ks)*64+lane)*8 + j] = W_b[k][n],  k=ks*32+(lane>>4)*8+j, n=t*16+(lane&15)
__global__ __launch_bounds__(256) void k_wprep(const void* __restrict__ gw, const void* __restrict__ l1w,
                                               u16* __restrict__ Wf, int L, int* __restrict__ flag){
  __shared__ int cnt;
  if (threadIdx.x == 0) cnt = 0;
  __syncthreads();
  int local = 0;
  for (int i = threadIdx.x; i < 4096; i += 256){
    u32 e = (((const u32*)gw)[i] >> 7) & 0xFFu;
    if (e >= 100u && e < 127u) local++;
  }
  atomicAdd(&cnt, local);
  __syncthreads();
  const int isbf = (cnt > 2048) ? 1 : 0;
  if (blockIdx.x == 0 && threadIdx.x == 0) *flag = isbf;

  const int b = blockIdx.x;
  const void* src = (b < L) ? gw : l1w;
  const int sbase = (b < L) ? b * 16384 : 0;
  u16* dst = Wf + (size_t)b * 16384;
  for (int g = threadIdx.x; g < 2048; g += 256){
    const int t = g >> 8, ks = (g >> 6) & 3, lane = g & 63;
    const int n = t * 16 + (lane & 15);
    const int k0 = ks * 32 + ((lane >> 4) << 3);
    u16* d = dst + (size_t)g * 8;
    #pragma unroll
    for (int j = 0; j < 8; ++j){
      d[j] = ftobf(ldf(src, sbase + (k0 + j) * 128 + n, isbf));
    }
  }
}

// ---- x -> bf16 Hb (fp32 path only; bf16 path reads x directly in k_mm) ----
__global__ __launch_bounds__(256) void k_cvt(const void* __restrict__ in, u16* __restrict__ out, int n8,
                                             const int* __restrict__ fl){
  if (*fl) return;
  int i = blockIdx.x * 256 + threadIdx.x;
  if (i >= n8) return;
  const float4 a = ((const float4*)in)[i * 2];
  const float4 b = ((const float4*)in)[i * 2 + 1];
  u16* o = out + (size_t)i * 8;
  o[0] = ftobf(a.x); o[1] = ftobf(a.y); o[2] = ftobf(a.z); o[3] = ftobf(a.w);
  o[4] = ftobf(b.x); o[5] = ftobf(b.y); o[6] = ftobf(b.z); o[7] = ftobf(b.w);
}

// ---- degree count over dst ----
__global__ __launch_bounds__(256) void k_count(const int* __restrict__ dst, int* __restrict__ cnt, int nE){
  int i = blockIdx.x * 256 + threadIdx.x;
  if (i < nE) atomicAdd(&cnt[dst[i]], 1);
}

// ---- exclusive scan of cnt -> boff ; also dinv = rsqrt(cnt+1) ----
__global__ __launch_bounds__(256) void k_scan1(const int* __restrict__ cnt, int* __restrict__ boff,
                                               int* __restrict__ bsum, float* __restrict__ dinv, int n){
  __shared__ int sm[256];
  int t = threadIdx.x;
  int i = blockIdx.x * 256 + t;
  int v = (i < n) ? cnt[i] : 0;
  if (i < n) dinv[i] = rsqrtf((float)v + 1.0f);
  sm[t] = v; __syncthreads();
  for (int off = 1; off < 256; off <<= 1){
    int add = (t >= off) ? sm[t - off] : 0;
    __syncthreads();
    sm[t] += add;
    __syncthreads();
  }
  if (i < n) boff[i] = sm[t] - v;
  if (t == 255) bsum[blockIdx.x] = sm[255];
}

__global__ __launch_bounds__(512) void k_scan2(int* __restrict__ bsum, int nb){
  __shared__ int sm[512];
  int t = threadIdx.x;
  int v = (t < nb) ? bsum[t] : 0;
  sm[t] = v; __syncthreads();
  for (int off = 1; off < 512; off <<= 1){
    int add = (t >= off) ? sm[t - off] : 0;
    __syncthreads();
    sm[t] += add;
    __syncthreads();
  }
  if (t < nb) bsum[t] = sm[t] - v;
}

// ---- boff fixup + goff[g] = first node of graph g (batch sorted) ----
__global__ __launch_bounds__(256) void k_scan3(int* __restrict__ boff, const int* __restrict__ bsum,
                                               int n, int nE, const int* __restrict__ batch,
                                               int* __restrict__ goff, int G){
  int i = blockIdx.x * 256 + threadIdx.x;
  if (i >= n) return;
  boff[i] += bsum[blockIdx.x];
  if (i == 0) boff[n] = nE;
  int b = batch[i];
  int prev = (i == 0) ? -1 : batch[i - 1];
  for (int g = prev + 1; g <= b; ++g) goff[g] = i;
  if (i == n - 1){
    for (int g = b + 1; g <= G; ++g) goff[g] = n;
  }
}

// ---- counting-sort edges by dst: eid[slot] = src ----
__global__ __launch_bounds__(256) void k_fill(const int* __restrict__ src, const int* __restrict__ dst,
                                              int* __restrict__ cnt, const int* __restrict__ boff,
                                              int* __restrict__ eid, int nE){
  int e = blockIdx.x * 256 + threadIdx.x;
  if (e >= nE) return;
  int d = dst[e];
  int old = atomicSub(&cnt[d], 1);
  eid[boff[d] + old - 1] = src[e];
}

// ---- GCN matmul: Ts[n,128] = (A[n,128] @ W) * dinv[row], bf16 out, LDS-repacked stores ----
// LDS tile stride 132 u16: write banks conflict-free (quad stride 264B = +8 banks), reads 2-way.
__global__ __launch_bounds__(256) void k_mm(const void* __restrict__ X, const u16* __restrict__ Hb, int use_x,
                                            const u16* __restrict__ Wf, const float* __restrict__ dinv,
                                            u16* __restrict__ T, int n, const int* __restrict__ fl){
  __shared__ u16 sm[4][16 * 132];
  const int isbf = *fl;
  const u16* A = (use_x && isbf) ? (const u16*)X : Hb;
  const int wave = threadIdx.x >> 6, lane = threadIdx.x & 63;
  const int m0 = blockIdx.x * 64 + wave * 16;
  int arow = m0 + (lane & 15); if (arow > n - 1) arow = n - 1;
  const u16* aptr = A + (size_t)arow * 128 + ((lane >> 4) << 3);

  f32x4 acc[8];
  #pragma unroll
  for (int t = 0; t < 8; ++t) acc[t] = (f32x4){0.f, 0.f, 0.f, 0.f};

  #pragma unroll
  for (int ks = 0; ks < 4; ++ks){
    const bf16x8 a = *(const bf16x8*)(aptr + ks * 32);
    #pragma unroll
    for (int t = 0; t < 8; ++t){
      const bf16x8 b = *(const bf16x8*)(Wf + (size_t)(((t * 4 + ks) * 64 + lane) * 8));
      acc[t] = __builtin_amdgcn_mfma_f32_16x16x32_bf16(a, b, acc[t], 0, 0, 0);
    }
  }

  const int quad = lane >> 4, col0 = lane & 15;
  float dv[4];
  #pragma unroll
  for (int r = 0; r < 4; ++r){
    const int row = m0 + quad * 4 + r;
    dv[r] = (row < n) ? dinv[row] : 0.f;
  }
  u16* my = sm[wave];
  #pragma unroll
  for (int t = 0; t < 8; ++t){
    #pragma unroll
    for (int r = 0; r < 4; ++r){
      my[(quad * 4 + r) * 132 + t * 16 + col0] = ftobf(acc[t][r] * dv[r]);
    }
  }
  __syncthreads();
  #pragma unroll
  for (int i = 0; i < 4; ++i){
    const int row = i * 4 + (lane >> 4);
    const int grow = m0 + row;
    const int c8 = (lane & 15) * 8;     // u16 col
    if (grow < n){
      const u16* s = &my[row * 132 + c8];
      uint2 lo = *(const uint2*)(s);
      uint2 hi = *(const uint2*)(s + 4);
      uint4 v = make_uint4(lo.x, lo.y, hi.x, hi.y);
      *(uint4*)&T[(size_t)grow * 128 + c8] = v;
    }
  }
}

// ---- fused head: s = relu(A@W1 + b1).w2 + b2, mask, write s (no atomics) ----
__global__ __launch_bounds__(256) void k_mmhead(const u16* __restrict__ Hb, const u16* __restrict__ Wf,
                                                const void* __restrict__ b1, const void* __restrict__ w2,
                                                const void* __restrict__ b2, const int* __restrict__ mask,
                                                float* __restrict__ s, int n, const int* __restrict__ fl){
  const int isbf = *fl;
  const int wave = threadIdx.x >> 6, lane = threadIdx.x & 63;
  const int m0 = blockIdx.x * 64 + wave * 16;
  int arow = m0 + (lane & 15); if (arow > n - 1) arow = n - 1;
  const u16* aptr = Hb + (size_t)arow * 128 + ((lane >> 4) << 3);

  f32x4 acc[8];
  #pragma unroll
  for (int t = 0; t < 8; ++t) acc[t] = (f32x4){0.f, 0.f, 0.f, 0.f};

  #pragma unroll
  for (int ks = 0; ks < 4; ++ks){
    const bf16x8 a = *(const bf16x8*)(aptr + ks * 32);
    #pragma unroll
    for (int t = 0; t < 8; ++t){
      const bf16x8 b = *(const bf16x8*)(Wf + (size_t)(((t * 4 + ks) * 64 + lane) * 8));
      acc[t] = __builtin_amdgcn_mfma_f32_16x16x32_bf16(a, b, acc[t], 0, 0, 0);
    }
  }

  const int quad = lane >> 4, col0 = lane & 15;
  float rs0 = 0.f, rs1 = 0.f, rs2 = 0.f, rs3 = 0.f;
  #pragma unroll
  for (int t = 0; t < 8; ++t){
    const int col = t * 16 + col0;
    const float bv = ldf(b1, col, isbf);
    const float wv = ldf(w2, col, isbf);
    rs0 = fmaf(fmaxf(acc[t][0] + bv, 0.f), wv, rs0);
    rs1 = fmaf(fmaxf(acc[t][1] + bv, 0.f), wv, rs1);
    rs2 = fmaf(fmaxf(acc[t][2] + bv, 0.f), wv, rs2);
    rs3 = fmaf(fmaxf(acc[t][3] + bv, 0.f), wv, rs3);
  }
  #pragma unroll
  for (int k = 1; k < 16; k <<= 1){
    rs0 += __shfl_xor(rs0, k);
    rs1 += __shfl_xor(rs1, k);
    rs2 += __shfl_xor(rs2, k);
    rs3 += __shfl_xor(rs3, k);
  }
  if (col0 < 4){
    const int row = m0 + quad * 4 + col0;
    if (row < n){
      float sc = (col0 == 0 ? rs0 : col0 == 1 ? rs1 : col0 == 2 ? rs2 : rs3) + ldf(b2, 0, isbf);
      if (mask[row] == 0) sc = -1e9f;
      s[row] = sc;
    }
  }
}

// ---- H[i] = (sum_{e->i} Ts[src] + Ts[i]) * dinv[i] + b[layer]; opt relu ----
// 4 nodes per wave: 16 lanes x uint4 (16B) per 256B row — full dwordx4 coalescing,
// 4 independent edge streams per wave for MLP.
__global__ __launch_bounds__(256) void k_gather(const u16* __restrict__ T, const int* __restrict__ boff,
                                                const int* __restrict__ eid, const float* __restrict__ dinv,
                                                const void* __restrict__ bias, int layer,
                                                u16* __restrict__ H, int n, int relu,
                                                const int* __restrict__ fl){
  const int wave = threadIdx.x >> 6, lane = threadIdx.x & 63;
  const int sub = lane >> 4, l16 = lane & 15;
  const int node = blockIdx.x * 16 + wave * 4 + sub;
  if (node >= n) return;
  const int isbf = *fl;
  const float di = dinv[node];
  const uint4 sv = ((const uint4*)(T + (size_t)node * 128))[l16];
  float acc0 = lo16(sv.x), acc1 = hi16(sv.x), acc2 = lo16(sv.y), acc3 = hi16(sv.y);
  float acc4 = lo16(sv.z), acc5 = hi16(sv.z), acc6 = lo16(sv.w), acc7 = hi16(sv.w);

  int j = boff[node];
  const int b1 = boff[node + 1];
  for (; j + 4 <= b1; j += 4){
    const int s0 = eid[j], s1 = eid[j + 1], s2 = eid[j + 2], s3 = eid[j + 3];
    const uint4 v0 = ((const uint4*)(T + (size_t)s0 * 128))[l16];
    const uint4 v1 = ((const uint4*)(T + (size_t)s1 * 128))[l16];
    const uint4 v2 = ((const uint4*)(T + (size_t)s2 * 128))[l16];
    const uint4 v3 = ((const uint4*)(T + (size_t)s3 * 128))[l16];
    acc0 += (lo16(v0.x) + lo16(v1.x)) + (lo16(v2.x) + lo16(v3.x));
    acc1 += (hi16(v0.x) + hi16(v1.x)) + (hi16(v2.x) + hi16(v3.x));
    acc2 += (lo16(v0.y) + lo16(v1.y)) + (lo16(v2.y) + lo16(v3.y));
    acc3 += (hi16(v0.y) + hi16(v1.y)) + (hi16(v2.y) + hi16(v3.y));
    acc4 += (lo16(v0.z) + lo16(v1.z)) + (lo16(v2.z) + lo16(v3.z));
    acc5 += (hi16(v0.z) + hi16(v1.z)) + (hi16(v2.z) + hi16(v3.z));
    acc6 += (lo16(v0.w) + lo16(v1.w)) + (lo16(v2.w) + lo16(v3.w));
    acc7 += (hi16(v0.w) + hi16(v1.w)) + (hi16(v2.w) + hi16(v3.w));
  }
  for (; j < b1; ++j){
    const uint4 v = ((const uint4*)(T + (size_t)eid[j] * 128))[l16];
    acc0 += lo16(v.x); acc1 += hi16(v.x);
    acc2 += lo16(v.y); acc3 += hi16(v.y);
    acc4 += lo16(v.z); acc5 += hi16(v.z);
    acc6 += lo16(v.w); acc7 += hi16(v.w);
  }
  const int bb = layer * 128 + l16 * 8;
  float h0 = fmaf(acc0, di, ldf(bias, bb + 0, isbf));
  float h1 = fmaf(acc1, di, ldf(bias, bb + 1, isbf));
  float h2 = fmaf(acc2, di, ldf(bias, bb + 2, isbf));
  float h3 = fmaf(acc3, di, ldf(bias, bb + 3, isbf));
  float h4 = fmaf(acc4, di, ldf(bias, bb + 4, isbf));
  float h5 = fmaf(acc5, di, ldf(bias, bb + 5, isbf));
  float h6 = fmaf(acc6, di, ldf(bias, bb + 6, isbf));
  float h7 = fmaf(acc7, di, ldf(bias, bb + 7, isbf));
  if (relu){
    h0 = fmaxf(h0, 0.f); h1 = fmaxf(h1, 0.f); h2 = fmaxf(h2, 0.f); h3 = fmaxf(h3, 0.f);
    h4 = fmaxf(h4, 0.f); h5 = fmaxf(h5, 0.f); h6 = fmaxf(h6, 0.f); h7 = fmaxf(h7, 0.f);
  }
  uint4 o;
  o.x = pack2(h0, h1); o.y = pack2(h2, h3); o.z = pack2(h4, h5); o.w = pack2(h6, h7);
  ((uint4*)(H + (size_t)node * 128))[l16] = o;
}

// ---- per-graph softmax: wave per graph, contiguous segment [goff[g], goff[g+1]) ----
__global__ __launch_bounds__(256) void k_gsm(const float* __restrict__ s, const int* __restrict__ goff,
                                             void* __restrict__ out, int G, const int* __restrict__ fl){
  const int g = blockIdx.x * 4 + (threadIdx.x >> 6);
  if (g >= G) return;
  const int lane = threadIdx.x & 63;
  const int i0 = goff[g], i1 = goff[g + 1];
  if (i0 >= i1) return;
  float m = -3.4e38f;
  for (int j = i0 + lane; j < i1; j += 64) m = fmaxf(m, s[j]);
  #pragma unroll
  for (int k = 32; k; k >>= 1) m = fmaxf(m, __shfl_xor(m, k));
  float zz = 0.f;
  for (int j = i0 + lane; j < i1; j += 64) zz += expf(s[j] - m);
  #pragma unroll
  for (int k = 32; k; k >>= 1) zz += __shfl_xor(zz, k);
  const float rz = 1.f / zz;
  const int isbf = *fl;
  for (int j = i0 + lane; j < i1; j += 64){
    const float v = expf(s[j] - m) * rz;
    if (isbf) ((u16*)out)[j] = ftobf(v);
    else      ((float*)out)[j] = v;
  }
}

extern "C" void kernel_launch(void* const* d_in, const int* in_sizes, int n_in,
                              void* d_out, int out_size, void* d_ws, size_t ws_size,
                              hipStream_t stream){
  const void* x    = d_in[0];
  const int* ei    = (const int*)d_in[1];
  const int* batch = (const int*)d_in[2];
  const int* mask  = (const int*)d_in[3];
  const void* gw   = d_in[4];
  const void* gb   = d_in[5];
  const void* l1w  = d_in[6];
  const void* l1b  = d_in[7];
  const void* l2w  = d_in[8];
  const void* l2b  = d_in[9];

  const int N = in_sizes[2];
  const int E = in_sizes[1] / 2;
  const int D = 128;
  const int L = in_sizes[4] / (D * D);
  const int G = 1000;   // from reference; not derivable from sizes

  char* p = (char*)d_ws;
  u16*  Hb    = (u16*)p;   p += (size_t)N * D * sizeof(u16);
  u16*  Tb    = (u16*)p;   p += (size_t)N * D * sizeof(u16);
  u16*  Wf    = (u16*)p;   p += (size_t)(L + 1) * D * D * sizeof(u16);
  float* dinv = (float*)p; p += (size_t)N * sizeof(float);
  float* sbuf = (float*)p; p += (size_t)N * sizeof(float);
  int*  cnt   = (int*)p;   p += (size_t)N * sizeof(int);
  int*  boff  = (int*)p;   p += (size_t)(N + 1) * sizeof(int);
  int*  bsum  = (int*)p;   p += 1024 * sizeof(int);
  int*  eid   = (int*)p;   p += (size_t)E * sizeof(int);
  int*  goff  = (int*)p;   p += (size_t)(G + 1) * sizeof(int);
  int*  flag  = (int*)p;   p += 256;

  const int* src  = ei;
  const int* dstp = ei + E;

  hipMemsetAsync(cnt, 0, (size_t)N * sizeof(int), stream);

  const int nb1 = (N + 255) / 256;
  const int mmg = (N + 63) / 64;
  const int ndg = (N + 15) / 16;
  const int n8  = N * D / 8;

  k_wprep<<<L + 1, 256, 0, stream>>>(gw, l1w, Wf, L, flag);
  k_cvt<<<(n8 + 255) / 256, 256, 0, stream>>>(x, Hb, n8, flag);

  k_count<<<(E + 255) / 256, 256, 0, stream>>>(dstp, cnt, E);
  k_scan1<<<nb1, 256, 0, stream>>>(cnt, boff, bsum, dinv, N);
  k_scan2<<<1, 512, 0, stream>>>(bsum, nb1);
  k_scan3<<<nb1, 256, 0, stream>>>(boff, bsum, N, E, batch, goff, G);
  k_fill<<<(E + 255) / 256, 256, 0, stream>>>(src, dstp, cnt, boff, eid, E);

  for (int l = 0; l < L; ++l){
    k_mm<<<mmg, 256, 0, stream>>>(x, Hb, (l == 0) ? 1 : 0, Wf + (size_t)l * D * D, dinv, Tb, N, flag);
    k_gather<<<ndg, 256, 0, stream>>>(Tb, boff, eid, dinv, gb, l, Hb, N, (l < L - 1) ? 1 : 0, flag);
  }
  k_mmhead<<<mmg, 256, 0, stream>>>(Hb, Wf + (size_t)L * D * D, l1b, l2w, l2b, mask, sbuf, N, flag);
  k_gsm<<<(G + 3) / 4, 256, 0, stream>>>(sbuf, goff, d_out, G, flag);
}